// Round 4
// baseline (1240.597 us; speedup 1.0000x reference)
//
#include <hip/hip_runtime.h>
#include <math.h>

#define NBLK 256
#define NTHR 512
#define LAYERS 4

typedef __attribute__((ext_vector_type(8)))  short bf16x8;
typedef __attribute__((ext_vector_type(4)))  short short4v;
typedef __attribute__((ext_vector_type(16))) float f32x16;

#define MFMA32 __builtin_amdgcn_mfma_f32_32x32x16_bf16
#define CROW(reg) (((reg) & 3) + 8 * ((reg) >> 2) + 4 * hi)

__device__ __forceinline__ unsigned short f2bf(float f) {
    union { float f; unsigned u; } x; x.f = f;
    unsigned r = x.u + 0x7fffu + ((x.u >> 16) & 1u);
    return (unsigned short)(r >> 16);
}

__device__ __forceinline__ unsigned cvtpk(float a, float b) {
    unsigned r;
    asm("v_cvt_pk_bf16_f32 %0, %1, %2" : "=v"(r) : "v"(a), "v"(b));
    return r;
}

union U8 { unsigned u[4]; bf16x8 v; };

// injective spread: task t -> wave floor(t*2048/ntask); wave recovers its task
__device__ __forceinline__ int spread_task(int gw, int ntask) {
    int t = (gw * ntask + 2047) >> 11;          // ceil(gw*ntask/2048)
    if (t >= ntask) return -1;
    return (((t << 11) / ntask) == gw) ? t : -1;
}

template<int K>
__device__ __forceinline__ void gcore(const short* __restrict__ Ab,
                                      const short* __restrict__ Wb,
                                      f32x16 acc[2]) {
    #pragma unroll 8
    for (int k0 = 0; k0 < K; k0 += 16) {
        bf16x8 a0 = *(const bf16x8*)(Ab + k0);
        bf16x8 a1 = *(const bf16x8*)(Ab + (size_t)32 * K + k0);
        bf16x8 b  = *(const bf16x8*)(Wb + k0);
        acc[0] = MFMA32(a0, b, acc[0], 0, 0, 0);
        acc[1] = MFMA32(a1, b, acc[1], 0, 0, 0);
    }
}

#define GBAR() do {                                                              \
    __syncthreads();                                                             \
    if (tid == 0) {                                                              \
        unsigned _old = __hip_atomic_fetch_add(bar, 1u, __ATOMIC_ACQ_REL,        \
                                               __HIP_MEMORY_SCOPE_AGENT);        \
        if (_old == NBLK - 1) {                                                  \
            __hip_atomic_store(bar, 0u, __ATOMIC_RELAXED,                        \
                               __HIP_MEMORY_SCOPE_AGENT);                        \
            __hip_atomic_store(bar + 1, ph + 1, __ATOMIC_RELEASE,                \
                               __HIP_MEMORY_SCOPE_AGENT);                        \
        } else {                                                                 \
            while (__hip_atomic_load(bar + 1, __ATOMIC_ACQUIRE,                  \
                                     __HIP_MEMORY_SCOPE_AGENT) <= ph)            \
                __builtin_amdgcn_s_sleep(2);                                     \
        }                                                                        \
    }                                                                            \
    ph++;                                                                        \
    __syncthreads();                                                             \
} while (0)

__global__ __launch_bounds__(NTHR, 4) void tt_kernel(
        const float* __restrict__ x,
        const float* __restrict__ Wq, const float* __restrict__ bq,
        const float* __restrict__ Wk, const float* __restrict__ bk,
        const float* __restrict__ Wv, const float* __restrict__ bv,
        const float* __restrict__ Wo, const float* __restrict__ bo,
        const float* __restrict__ W1, const float* __restrict__ b1,
        const float* __restrict__ W2, const float* __restrict__ b2,
        const float* __restrict__ g1, const float* __restrict__ bn1,
        const float* __restrict__ g2, const float* __restrict__ bn2,
        const float* __restrict__ Wf, const float* __restrict__ bf,
        float* __restrict__ out, char* __restrict__ ws) {
    float* xcur = (float*)(ws);
    short* x2b  = (short*)(ws + 3145728);
    short* qb   = (short*)(ws + 4718592);
    short* kb   = (short*)(ws + 6291456);
    short* vt   = (short*)(ws + 7077888);
    short* attb = (short*)(ws + 7864320);
    short* hbuf = (short*)(ws + 9437184);
    short* wbuf = (short*)(ws + 15728640);
    unsigned* bar = (unsigned*)(ws + 17301504);

    const int tid = threadIdx.x, bid = blockIdx.x;
    const int wv = tid >> 6, l = tid & 63, l31 = l & 31, hi = l >> 5;
    const int gw = bid * 8 + wv;                 // 0..2047
    unsigned ph = 0;

    // ---- phase: weight conversion fp32 -> bf16 ----
    for (int i4 = bid * NTHR + tid; i4 < 196608; i4 += NBLK * NTHR) {
        int idx = i4 * 4;
        const float* src; int off;
        if      (idx < 65536)  { src = Wq; off = idx; }
        else if (idx < 131072) { src = Wk; off = idx - 65536; }
        else if (idx < 196608) { src = Wv; off = idx - 131072; }
        else if (idx < 262144) { src = Wo; off = idx - 196608; }
        else if (idx < 524288) { src = W1; off = idx - 262144; }
        else                   { src = W2; off = idx - 524288; }
        float4 v = *(const float4*)(src + off);
        short4v o = { (short)f2bf(v.x), (short)f2bf(v.y),
                      (short)f2bf(v.z), (short)f2bf(v.w) };
        *(short4v*)(wbuf + idx) = o;
    }
    GBAR();

    auto ln_phase = [&](const float* src, const float* gg, const float* bbv) {
        #pragma unroll 1
        for (int rr = gw * 3; rr < gw * 3 + 3; ++rr) {
            const float* xp = src + (size_t)rr * 128;
            float2 v = *(const float2*)(xp + l * 2);
            float s1 = v.x + v.y, sq = v.x * v.x + v.y * v.y;
            #pragma unroll
            for (int o = 1; o < 64; o <<= 1) {
                s1 += __shfl_xor(s1, o); sq += __shfl_xor(sq, o);
            }
            float mean = s1 * (1.0f / 128.0f);
            float var = sq * (1.0f / 128.0f) - mean * mean;
            float rs = 1.0f / sqrtf(var + 1e-5f);
            float2 gv = *(const float2*)(gg + l * 2);
            float2 bv2 = *(const float2*)(bbv + l * 2);
            float ox = (v.x - mean) * rs * gv.x + bv2.x;
            float oy = (v.y - mean) * rs * gv.y + bv2.y;
            unsigned u = (unsigned)f2bf(ox) | ((unsigned)f2bf(oy) << 16);
            *(unsigned*)(x2b + (size_t)rr * 128 + l * 2) = u;
        }
    };

    for (int L = 0; L < LAYERS; ++L) {
        const short* wob = wbuf + 196608 + L * 16384;
        const short* w1b = wbuf + 262144 + L * 65536;
        const short* w2b = wbuf + 524288 + L * 65536;

        // ---- LN1 ----
        ln_phase(L == 0 ? x : xcur, g1 + L * 128, bn1 + L * 128);
        GBAR();

        // ---- QKV + RoPE + V-transpose (768 wave-tiles 64x32) ----
        {
            int t = spread_task(gw, 768);
            if (t >= 0) {
                int z, r0, c0;
                if (t < 384)      { z = 0; r0 = (t >> 2) * 64; c0 = (t & 3) * 32; }
                else if (t < 576) { int u = t - 384; z = 1; r0 = (u >> 2) * 64; c0 = (u & 3) * 32; }
                else              { int u = t - 576; z = 2; r0 = (u >> 2) * 64; c0 = (u & 3) * 32; }
                const short* Wz = wbuf + (z == 0 ? 0 : z == 1 ? 65536 : 131072) + L * 16384;
                const float* bz = (z == 0 ? bq : z == 1 ? bk : bv) + L * 128;
                int gadd = (z > 0) ? (r0 / 1536) * 1536 : 0;
                const short* Ab = x2b + (size_t)(r0 + gadd + l31) * 128 + hi * 8;
                const short* Wb2 = Wz + (size_t)(c0 + l31) * 128 + hi * 8;
                f32x16 acc[2];
                #pragma unroll
                for (int i = 0; i < 16; ++i) { acc[0][i] = 0.f; acc[1][i] = 0.f; }
                gcore<128>(Ab, Wb2, acc);
                int c = c0 + l31;
                float bbx = bz[c];
                int tt = (r0 >> 7) % 12;
                if (z < 2) {
                    short* dst = z ? kb : qb;
                    float sc = z ? 1.0f : 0.25f;       // fold HD^-0.5 into q
                    int cc = c & 15, i4 = c & 3;
                    float theta = (i4 == 0) ? 1.0f : 1e-4f;
                    float ang = (float)tt * theta;
                    float sn = sinf(ang), cs = cosf(ang);
                    #pragma unroll
                    for (int mi = 0; mi < 2; ++mi)
                    #pragma unroll
                    for (int reg = 0; reg < 16; ++reg) {
                        float v = acc[mi][reg] + bbx;
                        float pv = __shfl_xor(v, 4);   // partner column c^4
                        float vo = (cc < 4) ? (v * cs + pv * sn)
                                 : (cc < 8) ? (v * cs - pv * sn) : v;
                        vo *= sc;
                        int rr = r0 + mi * 32 + CROW(reg);
                        dst[(size_t)rr * 128 + c] = (short)f2bf(vo);
                    }
                } else {
                    int d = c & 15, hh = c >> 4, bidx = r0 / 1536;
                    #pragma unroll
                    for (int mi = 0; mi < 2; ++mi)
                    #pragma unroll
                    for (int rq = 0; rq < 4; ++rq) {
                        int rcb = r0 + mi * 32 + 8 * rq + 4 * hi;
                        int kk = rcb - bidx * 1536;
                        short4v o;
                        #pragma unroll
                        for (int j = 0; j < 4; ++j) o[j] = (short)f2bf(acc[mi][4 * rq + j] + bbx);
                        *(short4v*)(vt + ((size_t)(bidx * 8 + hh) * 16 + d) * 1536 + kk) = o;
                    }
                }
            }
        }
        GBAR();

        // ---- attention (1536 wave-tasks; defer-max online softmax) ----
        {
            int st = spread_task(gw, 1536);
            if (st >= 0) {
                int t = (st & 7) * 192 + (st >> 3);      // band-permute for balance
                int tq = 11 - (t >> 7);
                int r = t & 127;
                int h = r >> 4, bs = (r >> 2) & 3, qg = r & 3, b = bs >> 1;
                int q0 = (bs * 12 + tq) * 128 + qg * 32;
                bf16x8 qf = *(const bf16x8*)(qb + (size_t)(q0 + l31) * 128 + h * 16 + hi * 8);
                const short* kp = kb + (size_t)(b * 1536 + l31) * 128 + h * 16 + hi * 8;
                const short* vp = vt + ((size_t)(b * 8 + h) * 16 + l31) * 1536 + hi * 8;
                bool vload = l31 < 16;
                f32x16 acc, zv;
                #pragma unroll
                for (int i = 0; i < 16; ++i) { acc[i] = 0.f; zv[i] = 0.f; }
                float m = -1e30f, lsum = 0.f;
                int nch = (tq + 1) * 4;
                for (int c = 0; c < nch; ++c) {
                    bf16x8 kf = *(const bf16x8*)(kp + (size_t)c * 32 * 128);
                    f32x16 s = MFMA32(kf, qf, zv, 0, 0, 0);   // S^T[key][q=l31]
                    float cm = s[0];
                    #pragma unroll
                    for (int j = 1; j < 16; ++j) cm = fmaxf(cm, s[j]);
                    cm = fmaxf(cm, __shfl_xor(cm, 32));
                    if (__any(cm > m + 8.0f)) {               // defer-max rescale
                        float mn = fmaxf(m, cm);
                        float corr = __expf(m - mn);
                        m = mn;
                        lsum *= corr;
                        #pragma unroll
                        for (int rr = 0; rr < 8; ++rr) acc[rr] *= corr;
                    }
                    float ps = 0.f;
                    #pragma unroll
                    for (int j = 0; j < 16; ++j) { s[j] = __expf(s[j] - m); ps += s[j]; }
                    ps += __shfl_xor(ps, 32);
                    lsum += ps;
                    unsigned w0 = cvtpk(s[0],  s[1]),  w1 = cvtpk(s[2],  s[3]);
                    unsigned w2 = cvtpk(s[4],  s[5]),  w3 = cvtpk(s[6],  s[7]);
                    unsigned w4 = cvtpk(s[8],  s[9]),  w5 = cvtpk(s[10], s[11]);
                    unsigned w6 = cvtpk(s[12], s[13]), w7 = cvtpk(s[14], s[15]);
                    unsigned t1 = hi ? w0 : w2, t2 = hi ? w1 : w3;
                    unsigned t3 = hi ? w4 : w6, t4 = hi ? w5 : w7;
                    unsigned x1 = __shfl_xor((int)t1, 32), x2 = __shfl_xor((int)t2, 32);
                    unsigned x3 = __shfl_xor((int)t3, 32), x4 = __shfl_xor((int)t4, 32);
                    U8 pb1, pb2;
                    pb1.u[0] = hi ? x1 : w0;  pb1.u[1] = hi ? x2 : w1;
                    pb1.u[2] = hi ? w2 : x1;  pb1.u[3] = hi ? w3 : x2;
                    pb2.u[0] = hi ? x3 : w4;  pb2.u[1] = hi ? x4 : w5;
                    pb2.u[2] = hi ? w6 : x3;  pb2.u[3] = hi ? w7 : x4;
                    bf16x8 vf1, vf2;
                    #pragma unroll
                    for (int i = 0; i < 8; ++i) { vf1[i] = 0; vf2[i] = 0; }
                    if (vload) {
                        vf1 = *(const bf16x8*)(vp + c * 32);
                        vf2 = *(const bf16x8*)(vp + c * 32 + 16);
                    }
                    acc = MFMA32(vf1, pb1.v, acc, 0, 0, 0);
                    acc = MFMA32(vf2, pb2.v, acc, 0, 0, 0);
                }
                float linv = 1.0f / lsum;
                short4v o1, o2;
                #pragma unroll
                for (int j = 0; j < 4; ++j) o1[j] = (short)f2bf(acc[j] * linv);
                #pragma unroll
                for (int j = 0; j < 4; ++j) o2[j] = (short)f2bf(acc[4 + j] * linv);
                size_t base = (size_t)(q0 + l31) * 128 + h * 16;
                *(short4v*)(attb + base + 4 * hi) = o1;
                *(short4v*)(attb + base + 8 + 4 * hi) = o2;
            }
        }
        GBAR();

        // ---- out-proj + residual -> xcur (384 wave-tiles) ----
        {
            int t = spread_task(gw, 384);
            if (t >= 0) {
                int r0 = (t >> 2) * 64, c0 = (t & 3) * 32;
                const short* Ab = attb + (size_t)(r0 + l31) * 128 + hi * 8;
                const short* Wb2 = wob + (size_t)(c0 + l31) * 128 + hi * 8;
                f32x16 acc[2];
                #pragma unroll
                for (int i = 0; i < 16; ++i) { acc[0][i] = 0.f; acc[1][i] = 0.f; }
                gcore<128>(Ab, Wb2, acc);
                int c = c0 + l31;
                float bbx = bo[L * 128 + c];
                const float* res = (L == 0) ? x : xcur;
                #pragma unroll
                for (int mi = 0; mi < 2; ++mi)
                #pragma unroll
                for (int reg = 0; reg < 16; ++reg) {
                    int rr = r0 + mi * 32 + CROW(reg);
                    size_t ix = (size_t)rr * 128 + c;
                    xcur[ix] = res[ix] + acc[mi][reg] + bbx;
                }
            }
        }
        GBAR();

        // ---- LN2 ----
        ln_phase(xcur, g2 + L * 128, bn2 + L * 128);
        GBAR();

        // ---- FFN1 + GELU (1536 wave-tiles) ----
        {
            int t = spread_task(gw, 1536);
            if (t >= 0) {
                int r0 = (t >> 4) * 64, c0 = (t & 15) * 32;
                const short* Ab = x2b + (size_t)(r0 + l31) * 128 + hi * 8;
                const short* Wb2 = w1b + (size_t)(c0 + l31) * 128 + hi * 8;
                f32x16 acc[2];
                #pragma unroll
                for (int i = 0; i < 16; ++i) { acc[0][i] = 0.f; acc[1][i] = 0.f; }
                gcore<128>(Ab, Wb2, acc);
                int c = c0 + l31;
                float bbx = b1[L * 512 + c];
                #pragma unroll
                for (int mi = 0; mi < 2; ++mi)
                #pragma unroll
                for (int reg = 0; reg < 16; ++reg) {
                    int rr = r0 + mi * 32 + CROW(reg);
                    float v = acc[mi][reg] + bbx;
                    v = 0.5f * v * (1.0f + erff(v * 0.70710678118654752f));
                    hbuf[(size_t)rr * 512 + c] = (short)f2bf(v);
                }
            }
        }
        GBAR();

        // ---- FFN2 + residual -> xcur (384 wave-tiles, K=512) ----
        {
            int t = spread_task(gw, 384);
            if (t >= 0) {
                int r0 = (t >> 2) * 64, c0 = (t & 3) * 32;
                const short* Ab = hbuf + (size_t)(r0 + l31) * 512 + hi * 8;
                const short* Wb2 = w2b + (size_t)(c0 + l31) * 512 + hi * 8;
                f32x16 acc[2];
                #pragma unroll
                for (int i = 0; i < 16; ++i) { acc[0][i] = 0.f; acc[1][i] = 0.f; }
                gcore<512>(Ab, Wb2, acc);
                int c = c0 + l31;
                float bbx = b2[L * 128 + c];
                #pragma unroll
                for (int mi = 0; mi < 2; ++mi)
                #pragma unroll
                for (int reg = 0; reg < 16; ++reg) {
                    int rr = r0 + mi * 32 + CROW(reg);
                    size_t ix = (size_t)rr * 128 + c;
                    xcur[ix] = xcur[ix] + acc[mi][reg] + bbx;
                }
            }
        }
        GBAR();
    }

    // ---- final: out[n] = dot(x[n,:], Wf) + bf ----
    #pragma unroll 1
    for (int rr = gw * 3; rr < gw * 3 + 3; ++rr) {
        float2 xv = *(const float2*)(xcur + (size_t)rr * 128 + l * 2);
        float2 wv2 = *(const float2*)(Wf + l * 2);
        float s = xv.x * wv2.x + xv.y * wv2.y;
        #pragma unroll
        for (int o = 1; o < 64; o <<= 1) s += __shfl_xor(s, o);
        if (l == 0) out[rr] = s + bf[0];
    }
}

extern "C" void kernel_launch(void* const* d_in, const int* in_sizes, int n_in,
                              void* d_out, int out_size, void* d_ws, size_t ws_size,
                              hipStream_t stream) {
    char* wsb = (char*)d_ws;
    // zero the grid-barrier state (d_ws is poisoned 0xAA before every launch)
    hipMemsetAsync(wsb + 17301504, 0, 256, stream);
    tt_kernel<<<NBLK, NTHR, 0, stream>>>(
        (const float*)d_in[0],
        (const float*)d_in[1],  (const float*)d_in[2],
        (const float*)d_in[3],  (const float*)d_in[4],
        (const float*)d_in[5],  (const float*)d_in[6],
        (const float*)d_in[7],  (const float*)d_in[8],
        (const float*)d_in[9],  (const float*)d_in[10],
        (const float*)d_in[11], (const float*)d_in[12],
        (const float*)d_in[13], (const float*)d_in[14],
        (const float*)d_in[15], (const float*)d_in[16],
        (const float*)d_in[17], (const float*)d_in[18],
        (float*)d_out, wsb);
}

// Round 9
// 369.174 us; speedup vs baseline: 3.3605x; 3.3605x over previous
//
#include <hip/hip_runtime.h>
#include <hip/hip_bf16.h>
#include <math.h>

#define LAYERS 4
#define DIM    128
#define NH     8
#define TT     12
#define EE     128
#define BB     2
#define SS     2
#define HD     16
#define DFF    512
#define NROWS  (BB*SS*TT*EE)    // 6144
#define NKROWS (BB*TT*EE)       // 3072 (s=0 slice, compact)

typedef __attribute__((ext_vector_type(8)))  short bf16x8;
typedef __attribute__((ext_vector_type(4)))  short short4v;
typedef __attribute__((ext_vector_type(4)))  float f32x4;
typedef __attribute__((ext_vector_type(16))) float f32x16;

#define MFMA32 __builtin_amdgcn_mfma_f32_32x32x16_bf16

__device__ __forceinline__ unsigned short f2bf(float f) {
    union { float f; unsigned u; } x; x.f = f;
    unsigned r = x.u + 0x7fffu + ((x.u >> 16) & 1u);
    return (unsigned short)(r >> 16);
}

__device__ __forceinline__ unsigned cvtpk(float a, float b) {
    unsigned r;
    asm("v_cvt_pk_bf16_f32 %0, %1, %2" : "=v"(r) : "v"(a), "v"(b));
    return r;
}

union U8 { unsigned u[4]; bf16x8 v; };

// ---------------- weight fp32 -> bf16 conversion (once per launch) ----------
__global__ __launch_bounds__(256) void wconv_kernel(const float* __restrict__ Wq,
        const float* __restrict__ Wk, const float* __restrict__ Wv,
        const float* __restrict__ Wo, const float* __restrict__ W1,
        const float* __restrict__ W2, short* __restrict__ wbuf) {
    int idx = (blockIdx.x * 256 + threadIdx.x) * 4;
    const float* src; int off;
    if      (idx < 65536)  { src = Wq; off = idx; }
    else if (idx < 131072) { src = Wk; off = idx - 65536; }
    else if (idx < 196608) { src = Wv; off = idx - 131072; }
    else if (idx < 262144) { src = Wo; off = idx - 196608; }
    else if (idx < 524288) { src = W1; off = idx - 262144; }
    else                   { src = W2; off = idx - 524288; }
    float4 v = *(const float4*)(src + off);
    short4v o = { (short)f2bf(v.x), (short)f2bf(v.y), (short)f2bf(v.z), (short)f2bf(v.w) };
    *(short4v*)(wbuf + idx) = o;
}

// ---------------- LayerNorm: fp32 in, bf16 out; one wave per row -----------
__global__ __launch_bounds__(256) void ln_kernel(const float* __restrict__ x,
                                                 short* __restrict__ y,
                                                 const float* __restrict__ g,
                                                 const float* __restrict__ b) {
    int wave = threadIdx.x >> 6, lane = threadIdx.x & 63;
    int row = blockIdx.x * 4 + wave;
    const float* xp = x + (size_t)row * DIM;
    float2 v = *(const float2*)(xp + lane * 2);
    float s = v.x + v.y, sq = v.x * v.x + v.y * v.y;
    #pragma unroll
    for (int o = 1; o < 64; o <<= 1) { s += __shfl_xor(s, o); sq += __shfl_xor(sq, o); }
    float mean = s * (1.0f / 128.0f);
    float var = sq * (1.0f / 128.0f) - mean * mean;
    float rs = 1.0f / sqrtf(var + 1e-5f);
    float2 gv = *(const float2*)(g + lane * 2);
    float2 bv = *(const float2*)(b + lane * 2);
    float ox = (v.x - mean) * rs * gv.x + bv.x;
    float oy = (v.y - mean) * rs * gv.y + bv.y;
    unsigned u = (unsigned)f2bf(ox) | ((unsigned)f2bf(oy) << 16);
    *(unsigned*)(&y[(size_t)row * 128 + lane * 2]) = u;
}

// ------------- 32x32x16 GEMM core: wave tile 64 rows x 32 cols -------------
__device__ __forceinline__ void gemm_core32(const short* __restrict__ Ab,
                                            const short* __restrict__ Wb,
                                            int K, f32x16 acc[2]) {
    #pragma unroll 8
    for (int k0 = 0; k0 < K; k0 += 16) {
        bf16x8 a0 = *(const bf16x8*)(Ab + k0);
        bf16x8 a1 = *(const bf16x8*)(Ab + (size_t)32 * K + k0);
        bf16x8 b  = *(const bf16x8*)(Wb + k0);
        acc[0] = MFMA32(a0, b, acc[0], 0, 0, 0);
        acc[1] = MFMA32(a1, b, acc[1], 0, 0, 0);
    }
}

// ---------------- fused QKV projection + RoPE + V-transpose ----------------
// grid (2, 48, 3), block 256 (4 waves, block tile 128r x 64c).
__global__ __launch_bounds__(256) void qkv_kernel(const short* __restrict__ x2b,
        const short* __restrict__ wbuf, const float* __restrict__ bq,
        const float* __restrict__ bk, const float* __restrict__ bv, int layer,
        short* __restrict__ qb, short* __restrict__ kb, short* __restrict__ vt) {
    int z = blockIdx.z, by = blockIdx.y, bx = blockIdx.x;
    if (z > 0 && by >= 24) return;
    const short* Wz = wbuf + (z == 0 ? 0 : z == 1 ? 65536 : 131072) + layer * 16384;
    const float* bz = (z == 0 ? bq : z == 1 ? bk : bv) + layer * 128;
    int r0 = by * 128, c0 = bx * 64;
    int gadd = (z > 0) ? (by / 12) * 1536 : 0;     // compact kv row -> global row
    int tid = threadIdx.x, wv = tid >> 6, l = tid & 63, l31 = l & 31, hi = l >> 5;
    int wr = wv >> 1, wc = wv & 1;
    const short* Ab = x2b + (size_t)(r0 + gadd + wr * 64 + l31) * 128 + hi * 8;
    const short* Wb = Wz + (size_t)(c0 + wc * 32 + l31) * 128 + hi * 8;
    f32x16 acc[2];
    #pragma unroll
    for (int i = 0; i < 16; ++i) { acc[0][i] = 0.f; acc[1][i] = 0.f; }
    gemm_core32(Ab, Wb, 128, acc);
    int c = c0 + wc * 32 + l31;
    float bb = bz[c];
    int t = by % 12;
    if (z < 2) {
        short* dst = z ? kb : qb;
        float sc = z ? 1.0f : 0.25f;               // fold HD^-0.5 into q
        int cc = c & 15, i4 = c & 3;
        float theta = (i4 == 0) ? 1.0f : 1e-4f;
        float ang = (float)t * theta;
        float sn = sinf(ang), cs = cosf(ang);
        #pragma unroll
        for (int mi = 0; mi < 2; ++mi)
        #pragma unroll
        for (int reg = 0; reg < 16; ++reg) {
            float v = acc[mi][reg] + bb;
            float pv = __shfl_xor(v, 4);           // partner column c^4
            float vo = (cc < 4) ? (v * cs + pv * sn)
                     : (cc < 8) ? (v * cs - pv * sn) : v;
            vo *= sc;
            int r = r0 + wr * 64 + mi * 32 + (reg & 3) + 8 * (reg >> 2) + 4 * hi;
            dst[(size_t)r * 128 + c] = (short)f2bf(vo);
        }
    } else {
        int d = c & 15, hh = c >> 4, bidx = by / 12;
        #pragma unroll
        for (int mi = 0; mi < 2; ++mi)
        #pragma unroll
        for (int rq = 0; rq < 4; ++rq) {           // regs 4rq..4rq+3 -> kk consecutive
            int rcb = r0 + wr * 64 + mi * 32 + 8 * rq + 4 * hi;
            int kk = rcb - bidx * 1536;
            short4v o;
            #pragma unroll
            for (int j = 0; j < 4; ++j) o[j] = (short)f2bf(acc[mi][4 * rq + j] + bb);
            *(short4v*)(vt + ((size_t)(bidx * 8 + hh) * 16 + d) * 1536 + kk) = o;
        }
    }
}

// ---------------- flash attention, split-K partials ------------------------
// grid 1152 = 384 (tq desc, h, bs) x 3 splits; block 256 = 4 waves x 32 q.
// Split sp handles chunks c = sp, sp+3, ... of the (tq+1)*4 32-key chunks,
// with the exact R3 per-chunk body; writes per-lane {m, l, acc[8]}.
__global__ __launch_bounds__(256) void attn_part(const short* __restrict__ qb,
        const short* __restrict__ kb, const short* __restrict__ vt,
        float* __restrict__ part) {
    int bid = blockIdx.x;
    int blk = bid / 3, sp = bid - blk * 3;
    int tq = 11 - (blk >> 5);
    int hb = blk & 31, h = hb >> 2, bs = hb & 3, b = bs >> 1;
    int tid = threadIdx.x;
    int wv = tid >> 6, l = tid & 63, l31 = l & 31, hi = l >> 5;
    int q0 = (bs * 12 + tq) * 128 + wv * 32;
    bf16x8 qf = *(const bf16x8*)(qb + (size_t)(q0 + l31) * 128 + h * 16 + hi * 8);
    const short* kp = kb + (size_t)(b * 1536 + l31) * 128 + h * 16 + hi * 8;
    const short* vp = vt + ((size_t)(b * 8 + h) * 16 + l31) * 1536 + hi * 8;
    bool vload = l31 < 16;
    f32x16 acc, zv;
    #pragma unroll
    for (int i = 0; i < 16; ++i) { acc[i] = 0.f; zv[i] = 0.f; }
    float m = -1e30f, lsum = 0.f;
    int nch = (tq + 1) * 4;
    for (int c = sp; c < nch; c += 3) {
        bf16x8 kf = *(const bf16x8*)(kp + (size_t)c * 32 * 128);
        f32x16 s = MFMA32(kf, qf, zv, 0, 0, 0);    // S^T[key 0..31][q=l31]
        float cm = s[0];
        #pragma unroll
        for (int j = 1; j < 16; ++j) cm = fmaxf(cm, s[j]);
        cm = fmaxf(cm, __shfl_xor(cm, 32));
        float mn = fmaxf(m, cm);
        float corr = __expf(m - mn);
        m = mn;
        float p[16]; float ps = 0.f;
        #pragma unroll
        for (int j = 0; j < 16; ++j) { p[j] = __expf(s[j] - mn); ps += p[j]; }
        ps += __shfl_xor(ps, 32);
        lsum = lsum * corr + ps;
        #pragma unroll
        for (int r = 0; r < 8; ++r) acc[r] *= corr;   // rows>=16 stay 0
        unsigned w0 = cvtpk(p[0],  p[1]),  w1 = cvtpk(p[2],  p[3]);
        unsigned w2 = cvtpk(p[4],  p[5]),  w3 = cvtpk(p[6],  p[7]);
        unsigned w4 = cvtpk(p[8],  p[9]),  w5 = cvtpk(p[10], p[11]);
        unsigned w6 = cvtpk(p[12], p[13]), w7 = cvtpk(p[14], p[15]);
        unsigned t1 = hi ? w0 : w2, t2 = hi ? w1 : w3;
        unsigned t3 = hi ? w4 : w6, t4 = hi ? w5 : w7;
        unsigned x1 = __shfl_xor((int)t1, 32), x2 = __shfl_xor((int)t2, 32);
        unsigned x3 = __shfl_xor((int)t3, 32), x4 = __shfl_xor((int)t4, 32);
        U8 pb1, pb2;
        pb1.u[0] = hi ? x1 : w0;  pb1.u[1] = hi ? x2 : w1;
        pb1.u[2] = hi ? w2 : x1;  pb1.u[3] = hi ? w3 : x2;
        pb2.u[0] = hi ? x3 : w4;  pb2.u[1] = hi ? x4 : w5;
        pb2.u[2] = hi ? w6 : x3;  pb2.u[3] = hi ? w7 : x4;
        bf16x8 vf1, vf2;
        #pragma unroll
        for (int i = 0; i < 8; ++i) { vf1[i] = 0; vf2[i] = 0; }
        if (vload) {
            vf1 = *(const bf16x8*)(vp + c * 32);
            vf2 = *(const bf16x8*)(vp + c * 32 + 16);
        }
        acc = MFMA32(vf1, pb1.v, acc, 0, 0, 0);    // keys c*32+0..15
        acc = MFMA32(vf2, pb2.v, acc, 0, 0, 0);    // keys c*32+16..31
    }
    float* pp = part + ((size_t)bid * 256 + tid) * 10;
    pp[0] = m; pp[1] = lsum;
    #pragma unroll
    for (int j = 0; j < 8; ++j) pp[2 + j] = acc[j];
}

// ---------------- combine 3 partials, normalize, store ---------------------
// grid 384 blocks x 256; same (blk, lane) mapping as attn_part.
__global__ __launch_bounds__(256) void attn_comb(const float* __restrict__ part,
        short* __restrict__ attb) {
    int blk = blockIdx.x;
    int tq = 11 - (blk >> 5);
    int hb = blk & 31, h = hb >> 2, bs = hb & 3;
    int tid = threadIdx.x;
    int wv = tid >> 6, l = tid & 63, l31 = l & 31, hi = l >> 5;
    int q0 = (bs * 12 + tq) * 128 + wv * 32;
    const float* p0 = part + ((size_t)(blk * 3) * 256 + tid) * 10;
    const float* p1 = p0 + 2560;
    const float* p2 = p1 + 2560;
    float m0 = p0[0], m1 = p1[0], m2 = p2[0];
    float mm = fmaxf(fmaxf(m0, m1), m2);
    float e0 = __expf(m0 - mm), e1 = __expf(m1 - mm), e2 = __expf(m2 - mm);
    float lsum = p0[1] * e0 + p1[1] * e1 + p2[1] * e2;
    float linv = 1.0f / lsum;
    short4v o1, o2;
    #pragma unroll
    for (int j = 0; j < 4; ++j)
        o1[j] = (short)f2bf((p0[2 + j] * e0 + p1[2 + j] * e1 + p2[2 + j] * e2) * linv);
    #pragma unroll
    for (int j = 0; j < 4; ++j)
        o2[j] = (short)f2bf((p0[6 + j] * e0 + p1[6 + j] * e1 + p2[6 + j] * e2) * linv);
    size_t base = (size_t)(q0 + l31) * 128 + h * 16;
    *(short4v*)(attb + base + 4 * hi) = o1;        // d = 4hi..4hi+3
    *(short4v*)(attb + base + 8 + 4 * hi) = o2;    // d = 8+4hi..+3
}

// ---------------- GEMM + residual add into fp32 C (N=128) ------------------
__global__ __launch_bounds__(256) void res_gemm(const short* __restrict__ A,
        const short* __restrict__ W, const float* __restrict__ bias,
        float* __restrict__ C, int K) {
    int by = blockIdx.y, bx = blockIdx.x;
    int r0 = by * 128, c0 = bx * 64;
    int tid = threadIdx.x, wv = tid >> 6, l = tid & 63, l31 = l & 31, hi = l >> 5;
    int wr = wv >> 1, wc = wv & 1;
    const short* Ab = A + (size_t)(r0 + wr * 64 + l31) * K + hi * 8;
    const short* Wb = W + (size_t)(c0 + wc * 32 + l31) * K + hi * 8;
    f32x16 acc[2];
    #pragma unroll
    for (int i = 0; i < 16; ++i) { acc[0][i] = 0.f; acc[1][i] = 0.f; }
    gemm_core32(Ab, Wb, K, acc);
    int c = c0 + wc * 32 + l31;
    float bb = bias[c];
    #pragma unroll
    for (int mi = 0; mi < 2; ++mi)
    #pragma unroll
    for (int reg = 0; reg < 16; ++reg) {
        int r = r0 + wr * 64 + mi * 32 + (reg & 3) + 8 * (reg >> 2) + 4 * hi;
        C[(size_t)r * 128 + c] += acc[mi][reg] + bb;
    }
}

// ---------------- GEMM + exact GELU -> bf16 (N=512, K=128) -----------------
__global__ __launch_bounds__(256) void gelu_gemm(const short* __restrict__ A,
        const short* __restrict__ W, const float* __restrict__ bias,
        short* __restrict__ H) {
    int by = blockIdx.y, bx = blockIdx.x;
    int r0 = by * 128, c0 = bx * 64;
    int tid = threadIdx.x, wv = tid >> 6, l = tid & 63, l31 = l & 31, hi = l >> 5;
    int wr = wv >> 1, wc = wv & 1;
    const short* Ab = A + (size_t)(r0 + wr * 64 + l31) * 128 + hi * 8;
    const short* Wb = W + (size_t)(c0 + wc * 32 + l31) * 128 + hi * 8;
    f32x16 acc[2];
    #pragma unroll
    for (int i = 0; i < 16; ++i) { acc[0][i] = 0.f; acc[1][i] = 0.f; }
    gemm_core32(Ab, Wb, 128, acc);
    int c = c0 + wc * 32 + l31;
    float bb = bias[c];
    #pragma unroll
    for (int mi = 0; mi < 2; ++mi)
    #pragma unroll
    for (int reg = 0; reg < 16; ++reg) {
        int r = r0 + wr * 64 + mi * 32 + (reg & 3) + 8 * (reg >> 2) + 4 * hi;
        float v = acc[mi][reg] + bb;
        v = 0.5f * v * (1.0f + erff(v * 0.70710678118654752f));
        H[(size_t)r * 512 + c] = (short)f2bf(v);
    }
}

// ---------------- Final: out[n] = dot(x[n,:], Wf) + bf ----------------
__global__ __launch_bounds__(256) void final_kernel(const float* __restrict__ x,
        const float* __restrict__ Wf, const float* __restrict__ bf,
        float* __restrict__ out) {
    int wave = threadIdx.x >> 6, lane = threadIdx.x & 63;
    int row = blockIdx.x * 4 + wave;
    float2 xv = *(const float2*)(x + (size_t)row * DIM + lane * 2);
    float2 wv = *(const float2*)(Wf + lane * 2);
    float s = xv.x * wv.x + xv.y * wv.y;
    #pragma unroll
    for (int o = 1; o < 64; o <<= 1) s += __shfl_xor(s, o);
    if (lane == 0) out[row] = s + bf[0];
}

// ---------------- Launch ----------------
extern "C" void kernel_launch(void* const* d_in, const int* in_sizes, int n_in,
                              void* d_out, int out_size, void* d_ws, size_t ws_size,
                              hipStream_t stream) {
    const float* x   = (const float*)d_in[0];
    const float* Wq  = (const float*)d_in[1];
    const float* bq  = (const float*)d_in[2];
    const float* Wk  = (const float*)d_in[3];
    const float* bk  = (const float*)d_in[4];
    const float* Wv  = (const float*)d_in[5];
    const float* bv  = (const float*)d_in[6];
    const float* Wo  = (const float*)d_in[7];
    const float* bo  = (const float*)d_in[8];
    const float* W1  = (const float*)d_in[9];
    const float* b1  = (const float*)d_in[10];
    const float* W2  = (const float*)d_in[11];
    const float* b2  = (const float*)d_in[12];
    const float* g1  = (const float*)d_in[13];
    const float* bn1 = (const float*)d_in[14];
    const float* g2  = (const float*)d_in[15];
    const float* bn2 = (const float*)d_in[16];
    const float* Wf  = (const float*)d_in[17];
    const float* bf  = (const float*)d_in[18];
    float* out = (float*)d_out;

    char* wsb = (char*)d_ws;
    float* xcur  = (float*)(wsb + 0);           // 3 MB fp32
    short* x2b   = (short*)(wsb + 3145728);     // 1.5 MB bf16
    short* qb    = (short*)(wsb + 4718592);     // 1.5 MB
    short* kb    = (short*)(wsb + 6291456);     // 0.75 MB
    short* vt    = (short*)(wsb + 7077888);     // 0.75 MB  [b][h][d][1536]
    short* attb  = (short*)(wsb + 7864320);     // 1.5 MB
    short* hb    = (short*)(wsb + 9437184);     // 6 MB
    short* wbuf  = (short*)(wsb + 15728640);    // 1.5 MB
    float* partb = (float*)(wsb + 17301504);    // 11.8 MB attn partials

    hipMemcpyAsync(xcur, x, (size_t)NROWS * DIM * sizeof(float),
                   hipMemcpyDeviceToDevice, stream);
    wconv_kernel<<<768, 256, 0, stream>>>(Wq, Wk, Wv, Wo, W1, W2, wbuf);

    for (int i = 0; i < LAYERS; ++i) {
        const short* wob = wbuf + 196608 + i * 16384;
        const short* w1b = wbuf + 262144 + i * 65536;
        const short* w2b = wbuf + 524288 + i * 65536;

        ln_kernel<<<NROWS / 4, 256, 0, stream>>>(xcur, x2b, g1 + i * DIM, bn1 + i * DIM);
        qkv_kernel<<<dim3(2, 48, 3), 256, 0, stream>>>(x2b, wbuf, bq, bk, bv, i, qb, kb, vt);
        attn_part<<<1152, 256, 0, stream>>>(qb, kb, vt, partb);
        attn_comb<<<384, 256, 0, stream>>>(partb, attb);
        res_gemm<<<dim3(2, 48), 256, 0, stream>>>(attb, wob, bo + i * DIM, xcur, 128);
        ln_kernel<<<NROWS / 4, 256, 0, stream>>>(xcur, x2b, g2 + i * DIM, bn2 + i * DIM);
        gelu_gemm<<<dim3(8, 48), 256, 0, stream>>>(x2b, w1b, b1 + i * DFF, hb);
        res_gemm<<<dim3(2, 48), 256, 0, stream>>>(hb, w2b, b2 + i * DIM, xcur, 512);
    }
    final_kernel<<<NROWS / 4, 256, 0, stream>>>(xcur, Wf, bf, out);
}

// Round 10
// 366.729 us; speedup vs baseline: 3.3829x; 1.0067x over previous
//
#include <hip/hip_runtime.h>
#include <hip/hip_bf16.h>
#include <math.h>

#define LAYERS 4
#define DIM    128
#define NH     8
#define TT     12
#define EE     128
#define BB     2
#define SS     2
#define HD     16
#define DFF    512
#define NROWS  (BB*SS*TT*EE)    // 6144
#define NKROWS (BB*TT*EE)       // 3072 (s=0 slice, compact)

typedef __attribute__((ext_vector_type(8)))  short bf16x8;
typedef __attribute__((ext_vector_type(4)))  short short4v;
typedef __attribute__((ext_vector_type(16))) float f32x16;

#define MFMA32 __builtin_amdgcn_mfma_f32_32x32x16_bf16
#define CROW(reg) (((reg) & 3) + 8 * ((reg) >> 2) + 4 * hi)

__device__ __forceinline__ unsigned short f2bf(float f) {
    union { float f; unsigned u; } x; x.f = f;
    unsigned r = x.u + 0x7fffu + ((x.u >> 16) & 1u);
    return (unsigned short)(r >> 16);
}

__device__ __forceinline__ unsigned cvtpk(float a, float b) {
    unsigned r;
    asm("v_cvt_pk_bf16_f32 %0, %1, %2" : "=v"(r) : "v"(a), "v"(b));
    return r;
}

union U8 { unsigned u[4]; bf16x8 v; };

// ---------------- weight fp32 -> bf16 conversion (once per launch) ----------
__global__ __launch_bounds__(256) void wconv_kernel(const float* __restrict__ Wq,
        const float* __restrict__ Wk, const float* __restrict__ Wv,
        const float* __restrict__ Wo, const float* __restrict__ W1,
        const float* __restrict__ W2, short* __restrict__ wbuf) {
    int idx = (blockIdx.x * 256 + threadIdx.x) * 4;
    const float* src; int off;
    if      (idx < 65536)  { src = Wq; off = idx; }
    else if (idx < 131072) { src = Wk; off = idx - 65536; }
    else if (idx < 196608) { src = Wv; off = idx - 131072; }
    else if (idx < 262144) { src = Wo; off = idx - 196608; }
    else if (idx < 524288) { src = W1; off = idx - 262144; }
    else                   { src = W2; off = idx - 524288; }
    float4 v = *(const float4*)(src + off);
    short4v o = { (short)f2bf(v.x), (short)f2bf(v.y), (short)f2bf(v.z), (short)f2bf(v.w) };
    *(short4v*)(wbuf + idx) = o;
}

// ---- block-cooperative LN of 128 rows into LDS tile At[128][136] (bf16) ----
// 512 threads: 4 per row, 32 elems each; shfl_xor(1,2) merges the 4 partials.
__device__ __forceinline__ void ln_to_lds(short (*At)[136], const float* __restrict__ xrow0,
                                          const float* __restrict__ gl,
                                          const float* __restrict__ bl, int tid) {
    int row = tid >> 2, sub = tid & 3;
    const float* xp = xrow0 + (size_t)row * 128 + sub * 32;
    float4 v[8];
    float s = 0.f, q = 0.f;
    #pragma unroll
    for (int i = 0; i < 8; ++i) {
        v[i] = *(const float4*)(xp + i * 4);
        s += v[i].x + v[i].y + v[i].z + v[i].w;
        q += v[i].x * v[i].x + v[i].y * v[i].y + v[i].z * v[i].z + v[i].w * v[i].w;
    }
    s += __shfl_xor(s, 1); q += __shfl_xor(q, 1);
    s += __shfl_xor(s, 2); q += __shfl_xor(q, 2);
    float mean = s * (1.0f / 128.0f);
    float rs = 1.0f / sqrtf(q * (1.0f / 128.0f) - mean * mean + 1e-5f);
    const float* gp = gl + sub * 32;
    const float* bp = bl + sub * 32;
    #pragma unroll
    for (int i = 0; i < 8; ++i) {
        float4 g4 = *(const float4*)(gp + i * 4);
        float4 b4 = *(const float4*)(bp + i * 4);
        unsigned u0 = cvtpk((v[i].x - mean) * rs * g4.x + b4.x,
                            (v[i].y - mean) * rs * g4.y + b4.y);
        unsigned u1 = cvtpk((v[i].z - mean) * rs * g4.z + b4.z,
                            (v[i].w - mean) * rs * g4.w + b4.w);
        unsigned long long uu = (unsigned long long)u0 | ((unsigned long long)u1 << 32);
        *(unsigned long long*)(&At[row][sub * 32 + i * 4]) = uu;
    }
}

// ---------------- fused LN1 + QKV + RoPE + V-transpose (LDS-staged) --------
// 96 blocks x 512 thr: bid<48 Q row-tiles; [48,72) K; [72,96) V. Each block:
// LN 128 rows -> LDS, then 8 waves x (64r x 32c) MFMA tiles covering 128x128.
__global__ __launch_bounds__(512) void qkv_lds(const float* __restrict__ xin,
        const short* __restrict__ wbuf, const float* __restrict__ bq,
        const float* __restrict__ bk, const float* __restrict__ bv, int layer,
        const float* __restrict__ gl, const float* __restrict__ bl,
        short* __restrict__ qb, short* __restrict__ kb, short* __restrict__ vt) {
    __shared__ short At[128][136];
    int bid = blockIdx.x;
    int z, by;
    if (bid < 48)      { z = 0; by = bid; }
    else if (bid < 72) { z = 1; by = bid - 48; }
    else               { z = 2; by = bid - 72; }
    const short* Wz = wbuf + (z == 0 ? 0 : z == 1 ? 65536 : 131072) + layer * 16384;
    const float* bz = (z == 0 ? bq : z == 1 ? bk : bv) + layer * 128;
    int r0 = by * 128;
    int gadd = (z > 0) ? (by / 12) * 1536 : 0;     // compact kv row -> global row
    int tid = threadIdx.x;

    ln_to_lds(At, xin + (size_t)(r0 + gadd) * 128, gl, bl, tid);
    __syncthreads();

    int wv = tid >> 6, l = tid & 63, l31 = l & 31, hi = l >> 5;
    int wr = wv >> 2, wc = wv & 3;                 // 2 row-halves x 4 col-tiles
    const short* Wb = Wz + (size_t)(wc * 32 + l31) * 128 + hi * 8;
    f32x16 acc[2];
    #pragma unroll
    for (int i = 0; i < 16; ++i) { acc[0][i] = 0.f; acc[1][i] = 0.f; }
    #pragma unroll 8
    for (int k0 = 0; k0 < 128; k0 += 16) {
        bf16x8 a0 = *(const bf16x8*)(&At[wr * 64 + l31][k0 + hi * 8]);
        bf16x8 a1 = *(const bf16x8*)(&At[wr * 64 + 32 + l31][k0 + hi * 8]);
        bf16x8 b  = *(const bf16x8*)(Wb + k0);
        acc[0] = MFMA32(a0, b, acc[0], 0, 0, 0);
        acc[1] = MFMA32(a1, b, acc[1], 0, 0, 0);
    }

    int c = wc * 32 + l31;
    float bb = bz[c];
    int t = by % 12;
    if (z < 2) {
        short* dst = z ? kb : qb;
        float sc = z ? 1.0f : 0.25f;               // fold HD^-0.5 into q
        int cc = c & 15, i4 = c & 3;
        float theta = (i4 == 0) ? 1.0f : 1e-4f;
        float ang = (float)t * theta;
        float sn = sinf(ang), cs = cosf(ang);
        #pragma unroll
        for (int mi = 0; mi < 2; ++mi)
        #pragma unroll
        for (int reg = 0; reg < 16; ++reg) {
            float v = acc[mi][reg] + bb;
            float pv = __shfl_xor(v, 4);           // partner column c^4
            float vo = (cc < 4) ? (v * cs + pv * sn)
                     : (cc < 8) ? (v * cs - pv * sn) : v;
            vo *= sc;
            int r = r0 + wr * 64 + mi * 32 + CROW(reg);
            dst[(size_t)r * 128 + c] = (short)f2bf(vo);
        }
    } else {
        int d = c & 15, hh = c >> 4, bidx = by / 12;
        #pragma unroll
        for (int mi = 0; mi < 2; ++mi)
        #pragma unroll
        for (int rq = 0; rq < 4; ++rq) {           // regs 4rq..4rq+3 -> kk consecutive
            int rcb = r0 + wr * 64 + mi * 32 + 8 * rq + 4 * hi;
            int kk = rcb - bidx * 1536;
            short4v o;
            #pragma unroll
            for (int j = 0; j < 4; ++j) o[j] = (short)f2bf(acc[mi][4 * rq + j] + bb);
            *(short4v*)(vt + ((size_t)(bidx * 8 + hh) * 16 + d) * 1536 + kk) = o;
        }
    }
}

// ---------------- flash attention, split-K partials (R9, unchanged) --------
__global__ __launch_bounds__(256) void attn_part(const short* __restrict__ qb,
        const short* __restrict__ kb, const short* __restrict__ vt,
        float* __restrict__ part) {
    int bid = blockIdx.x;
    int blk = bid / 3, sp = bid - blk * 3;
    int tq = 11 - (blk >> 5);
    int hb = blk & 31, h = hb >> 2, bs = hb & 3, b = bs >> 1;
    int tid = threadIdx.x;
    int wv = tid >> 6, l = tid & 63, l31 = l & 31, hi = l >> 5;
    int q0 = (bs * 12 + tq) * 128 + wv * 32;
    bf16x8 qf = *(const bf16x8*)(qb + (size_t)(q0 + l31) * 128 + h * 16 + hi * 8);
    const short* kp = kb + (size_t)(b * 1536 + l31) * 128 + h * 16 + hi * 8;
    const short* vp = vt + ((size_t)(b * 8 + h) * 16 + l31) * 1536 + hi * 8;
    bool vload = l31 < 16;
    f32x16 acc, zv;
    #pragma unroll
    for (int i = 0; i < 16; ++i) { acc[i] = 0.f; zv[i] = 0.f; }
    float m = -1e30f, lsum = 0.f;
    int nch = (tq + 1) * 4;
    for (int c = sp; c < nch; c += 3) {
        bf16x8 kf = *(const bf16x8*)(kp + (size_t)c * 32 * 128);
        f32x16 s = MFMA32(kf, qf, zv, 0, 0, 0);    // S^T[key 0..31][q=l31]
        float cm = s[0];
        #pragma unroll
        for (int j = 1; j < 16; ++j) cm = fmaxf(cm, s[j]);
        cm = fmaxf(cm, __shfl_xor(cm, 32));
        float mn = fmaxf(m, cm);
        float corr = __expf(m - mn);
        m = mn;
        float p[16]; float ps = 0.f;
        #pragma unroll
        for (int j = 0; j < 16; ++j) { p[j] = __expf(s[j] - mn); ps += p[j]; }
        ps += __shfl_xor(ps, 32);
        lsum = lsum * corr + ps;
        #pragma unroll
        for (int r = 0; r < 8; ++r) acc[r] *= corr;   // rows>=16 stay 0
        unsigned w0 = cvtpk(p[0],  p[1]),  w1 = cvtpk(p[2],  p[3]);
        unsigned w2 = cvtpk(p[4],  p[5]),  w3 = cvtpk(p[6],  p[7]);
        unsigned w4 = cvtpk(p[8],  p[9]),  w5 = cvtpk(p[10], p[11]);
        unsigned w6 = cvtpk(p[12], p[13]), w7 = cvtpk(p[14], p[15]);
        unsigned t1 = hi ? w0 : w2, t2 = hi ? w1 : w3;
        unsigned t3 = hi ? w4 : w6, t4 = hi ? w5 : w7;
        unsigned x1 = __shfl_xor((int)t1, 32), x2 = __shfl_xor((int)t2, 32);
        unsigned x3 = __shfl_xor((int)t3, 32), x4 = __shfl_xor((int)t4, 32);
        U8 pb1, pb2;
        pb1.u[0] = hi ? x1 : w0;  pb1.u[1] = hi ? x2 : w1;
        pb1.u[2] = hi ? w2 : x1;  pb1.u[3] = hi ? w3 : x2;
        pb2.u[0] = hi ? x3 : w4;  pb2.u[1] = hi ? x4 : w5;
        pb2.u[2] = hi ? w6 : x3;  pb2.u[3] = hi ? w7 : x4;
        bf16x8 vf1, vf2;
        #pragma unroll
        for (int i = 0; i < 8; ++i) { vf1[i] = 0; vf2[i] = 0; }
        if (vload) {
            vf1 = *(const bf16x8*)(vp + c * 32);
            vf2 = *(const bf16x8*)(vp + c * 32 + 16);
        }
        acc = MFMA32(vf1, pb1.v, acc, 0, 0, 0);    // keys c*32+0..15
        acc = MFMA32(vf2, pb2.v, acc, 0, 0, 0);    // keys c*32+16..31
    }
    float* pp = part + ((size_t)bid * 256 + tid) * 10;
    pp[0] = m; pp[1] = lsum;
    #pragma unroll
    for (int j = 0; j < 8; ++j) pp[2 + j] = acc[j];
}

// ---------------- combine 3 partials, normalize, store (R9, unchanged) -----
__global__ __launch_bounds__(256) void attn_comb(const float* __restrict__ part,
        short* __restrict__ attb) {
    int blk = blockIdx.x;
    int tq = 11 - (blk >> 5);
    int hb = blk & 31, h = hb >> 2, bs = hb & 3;
    int tid = threadIdx.x;
    int wv = tid >> 6, l = tid & 63, l31 = l & 31, hi = l >> 5;
    int q0 = (bs * 12 + tq) * 128 + wv * 32;
    const float* p0 = part + ((size_t)(blk * 3) * 256 + tid) * 10;
    const float* p1 = p0 + 2560;
    const float* p2 = p1 + 2560;
    float m0 = p0[0], m1 = p1[0], m2 = p2[0];
    float mm = fmaxf(fmaxf(m0, m1), m2);
    float e0 = __expf(m0 - mm), e1 = __expf(m1 - mm), e2 = __expf(m2 - mm);
    float lsum = p0[1] * e0 + p1[1] * e1 + p2[1] * e2;
    float linv = 1.0f / lsum;
    short4v o1, o2;
    #pragma unroll
    for (int j = 0; j < 4; ++j)
        o1[j] = (short)f2bf((p0[2 + j] * e0 + p1[2 + j] * e1 + p2[2 + j] * e2) * linv);
    #pragma unroll
    for (int j = 0; j < 4; ++j)
        o2[j] = (short)f2bf((p0[6 + j] * e0 + p1[6 + j] * e1 + p2[6 + j] * e2) * linv);
    size_t base = (size_t)(q0 + l31) * 128 + h * 16;
    *(short4v*)(attb + base + 4 * hi) = o1;        // d = 4hi..4hi+3
    *(short4v*)(attb + base + 8 + 4 * hi) = o2;    // d = 8+4hi..+3
}

// ------------- 32x32x16 GEMM core: wave tile 64 rows x 32 cols -------------
__device__ __forceinline__ void gemm_core32(const short* __restrict__ Ab,
                                            const short* __restrict__ Wb,
                                            int K, f32x16 acc[2]) {
    #pragma unroll 8
    for (int k0 = 0; k0 < K; k0 += 16) {
        bf16x8 a0 = *(const bf16x8*)(Ab + k0);
        bf16x8 a1 = *(const bf16x8*)(Ab + (size_t)32 * K + k0);
        bf16x8 b  = *(const bf16x8*)(Wb + k0);
        acc[0] = MFMA32(a0, b, acc[0], 0, 0, 0);
        acc[1] = MFMA32(a1, b, acc[1], 0, 0, 0);
    }
}

// ---------------- GEMM + bias + residual -> fp32 C (N=128) -----------------
__global__ __launch_bounds__(256) void res_gemm(const short* __restrict__ A,
        const short* __restrict__ W, const float* __restrict__ bias,
        const float* __restrict__ res, float* __restrict__ C, int K) {
    int by = blockIdx.y, bx = blockIdx.x;
    int r0 = by * 128, c0 = bx * 64;
    int tid = threadIdx.x, wv = tid >> 6, l = tid & 63, l31 = l & 31, hi = l >> 5;
    int wr = wv >> 1, wc = wv & 1;
    const short* Ab = A + (size_t)(r0 + wr * 64 + l31) * K + hi * 8;
    const short* Wb = W + (size_t)(c0 + wc * 32 + l31) * K + hi * 8;
    f32x16 acc[2];
    #pragma unroll
    for (int i = 0; i < 16; ++i) { acc[0][i] = 0.f; acc[1][i] = 0.f; }
    gemm_core32(Ab, Wb, K, acc);
    int c = c0 + wc * 32 + l31;
    float bb = bias[c];
    #pragma unroll
    for (int mi = 0; mi < 2; ++mi)
    #pragma unroll
    for (int reg = 0; reg < 16; ++reg) {
        int r = r0 + wr * 64 + mi * 32 + CROW(reg);
        size_t ix = (size_t)r * 128 + c;
        C[ix] = res[ix] + acc[mi][reg] + bb;
    }
}

// ---------------- fused LN2 + FFN1 + GELU -> bf16 (LDS-staged) -------------
// grid (4, 48) x 512 thr; each block 128 rows x 128 cols of the N=512 output.
__global__ __launch_bounds__(512) void ffn1_lds(const float* __restrict__ xin,
        const short* __restrict__ w1l, const float* __restrict__ b1l,
        const float* __restrict__ gl, const float* __restrict__ bl,
        short* __restrict__ H) {
    __shared__ short At[128][136];
    int by = blockIdx.y, bx = blockIdx.x;
    int r0 = by * 128;
    int tid = threadIdx.x;

    ln_to_lds(At, xin + (size_t)r0 * 128, gl, bl, tid);
    __syncthreads();

    int wv = tid >> 6, l = tid & 63, l31 = l & 31, hi = l >> 5;
    int wr = wv >> 2, wc = wv & 3;
    int c = bx * 128 + wc * 32 + l31;
    const short* Wb = w1l + (size_t)c * 128 + hi * 8;
    f32x16 acc[2];
    #pragma unroll
    for (int i = 0; i < 16; ++i) { acc[0][i] = 0.f; acc[1][i] = 0.f; }
    #pragma unroll 8
    for (int k0 = 0; k0 < 128; k0 += 16) {
        bf16x8 a0 = *(const bf16x8*)(&At[wr * 64 + l31][k0 + hi * 8]);
        bf16x8 a1 = *(const bf16x8*)(&At[wr * 64 + 32 + l31][k0 + hi * 8]);
        bf16x8 b  = *(const bf16x8*)(Wb + k0);
        acc[0] = MFMA32(a0, b, acc[0], 0, 0, 0);
        acc[1] = MFMA32(a1, b, acc[1], 0, 0, 0);
    }
    float bb = b1l[c];
    #pragma unroll
    for (int mi = 0; mi < 2; ++mi)
    #pragma unroll
    for (int reg = 0; reg < 16; ++reg) {
        int r = r0 + wr * 64 + mi * 32 + CROW(reg);
        float v = acc[mi][reg] + bb;
        v = 0.5f * v * (1.0f + erff(v * 0.70710678118654752f));
        H[(size_t)r * 512 + c] = (short)f2bf(v);
    }
}

// ---------------- Final: out[n] = dot(x[n,:], Wf) + bf ----------------
__global__ __launch_bounds__(256) void final_kernel(const float* __restrict__ x,
        const float* __restrict__ Wf, const float* __restrict__ bf,
        float* __restrict__ out) {
    int wave = threadIdx.x >> 6, lane = threadIdx.x & 63;
    int row = blockIdx.x * 4 + wave;
    float2 xv = *(const float2*)(x + (size_t)row * DIM + lane * 2);
    float2 wv = *(const float2*)(Wf + lane * 2);
    float s = xv.x * wv.x + xv.y * wv.y;
    #pragma unroll
    for (int o = 1; o < 64; o <<= 1) s += __shfl_xor(s, o);
    if (lane == 0) out[row] = s + bf[0];
}

// ---------------- Launch ----------------
extern "C" void kernel_launch(void* const* d_in, const int* in_sizes, int n_in,
                              void* d_out, int out_size, void* d_ws, size_t ws_size,
                              hipStream_t stream) {
    const float* x   = (const float*)d_in[0];
    const float* Wq  = (const float*)d_in[1];
    const float* bq  = (const float*)d_in[2];
    const float* Wk  = (const float*)d_in[3];
    const float* bk  = (const float*)d_in[4];
    const float* Wv  = (const float*)d_in[5];
    const float* bv  = (const float*)d_in[6];
    const float* Wo  = (const float*)d_in[7];
    const float* bo  = (const float*)d_in[8];
    const float* W1  = (const float*)d_in[9];
    const float* b1  = (const float*)d_in[10];
    const float* W2  = (const float*)d_in[11];
    const float* b2  = (const float*)d_in[12];
    const float* g1  = (const float*)d_in[13];
    const float* bn1 = (const float*)d_in[14];
    const float* g2  = (const float*)d_in[15];
    const float* bn2 = (const float*)d_in[16];
    const float* Wf  = (const float*)d_in[17];
    const float* bf  = (const float*)d_in[18];
    float* out = (float*)d_out;

    char* wsb = (char*)d_ws;
    float* xcur  = (float*)(wsb + 0);           // 3 MB fp32
    short* qb    = (short*)(wsb + 4718592);     // 1.5 MB
    short* kb    = (short*)(wsb + 6291456);     // 0.75 MB
    short* vt    = (short*)(wsb + 7077888);     // 0.75 MB  [b][h][d][1536]
    short* attb  = (short*)(wsb + 7864320);     // 1.5 MB
    short* hb    = (short*)(wsb + 9437184);     // 6 MB
    short* wbuf  = (short*)(wsb + 15728640);    // 1.5 MB
    float* partb = (float*)(wsb + 17301504);    // 11.8 MB attn partials

    wconv_kernel<<<768, 256, 0, stream>>>(Wq, Wk, Wv, Wo, W1, W2, wbuf);

    for (int i = 0; i < LAYERS; ++i) {
        const short* wob = wbuf + 196608 + i * 16384;
        const short* w1b = wbuf + 262144 + i * 65536;
        const short* w2b = wbuf + 524288 + i * 65536;
        const float* xin = (i == 0) ? x : xcur;

        qkv_lds<<<96, 512, 0, stream>>>(xin, wbuf, bq, bk, bv, i,
                g1 + i * DIM, bn1 + i * DIM, qb, kb, vt);
        attn_part<<<1152, 256, 0, stream>>>(qb, kb, vt, partb);
        attn_comb<<<384, 256, 0, stream>>>(partb, attb);
        res_gemm<<<dim3(2, 48), 256, 0, stream>>>(attb, wob, bo + i * DIM,
                xin, xcur, 128);
        ffn1_lds<<<dim3(4, 48), 512, 0, stream>>>(xcur, w1b, b1 + i * DFF,
                g2 + i * DIM, bn2 + i * DIM, hb);
        res_gemm<<<dim3(2, 48), 256, 0, stream>>>(hb, w2b, b2 + i * DIM,
                xcur, xcur, 512);
    }
    final_kernel<<<NROWS / 4, 256, 0, stream>>>(xcur, Wf, bf, out);
}

// Round 12
// 334.034 us; speedup vs baseline: 3.7140x; 1.0979x over previous
//
#include <hip/hip_runtime.h>
#include <hip/hip_bf16.h>
#include <math.h>

#define LAYERS 4
#define DIM    128
#define NH     8
#define TT     12
#define EE     128
#define BB     2
#define SS     2
#define HD     16
#define DFF    512
#define NROWS  (BB*SS*TT*EE)    // 6144
#define NKROWS (BB*TT*EE)       // 3072 (s=0 slice, compact)

typedef __attribute__((ext_vector_type(8)))  short bf16x8;
typedef __attribute__((ext_vector_type(4)))  short short4v;
typedef __attribute__((ext_vector_type(16))) float f32x16;

#define MFMA32 __builtin_amdgcn_mfma_f32_32x32x16_bf16
#define CROW(reg) (((reg) & 3) + 8 * ((reg) >> 2) + 4 * hi)

__device__ __forceinline__ unsigned short f2bf(float f) {
    union { float f; unsigned u; } x; x.f = f;
    unsigned r = x.u + 0x7fffu + ((x.u >> 16) & 1u);
    return (unsigned short)(r >> 16);
}

__device__ __forceinline__ unsigned cvtpk(float a, float b) {
    unsigned r;
    asm("v_cvt_pk_bf16_f32 %0, %1, %2" : "=v"(r) : "v"(a), "v"(b));
    return r;
}

union U8 { unsigned u[4]; bf16x8 v; };

// ---------------- weight fp32 -> bf16 conversion (once per launch) ----------
__global__ __launch_bounds__(256) void wconv_kernel(const float* __restrict__ Wq,
        const float* __restrict__ Wk, const float* __restrict__ Wv,
        const float* __restrict__ Wo, const float* __restrict__ W1,
        const float* __restrict__ W2, short* __restrict__ wbuf) {
    int idx = (blockIdx.x * 256 + threadIdx.x) * 4;
    const float* src; int off;
    if      (idx < 65536)  { src = Wq; off = idx; }
    else if (idx < 131072) { src = Wk; off = idx - 65536; }
    else if (idx < 196608) { src = Wv; off = idx - 131072; }
    else if (idx < 262144) { src = Wo; off = idx - 196608; }
    else if (idx < 524288) { src = W1; off = idx - 262144; }
    else                   { src = W2; off = idx - 524288; }
    float4 v = *(const float4*)(src + off);
    short4v o = { (short)f2bf(v.x), (short)f2bf(v.y), (short)f2bf(v.z), (short)f2bf(v.w) };
    *(short4v*)(wbuf + idx) = o;
}

// ---- block-cooperative LN of 64 rows into LDS tile At[64][136] (bf16) -----
// 256 threads: 4 per row, 32 elems each; shfl_xor(1,2) merges the 4 partials.
__device__ __forceinline__ void ln_to_lds64(short (*At)[136], const float* __restrict__ xrow0,
                                            const float* __restrict__ gl,
                                            const float* __restrict__ bl, int tid) {
    int row = tid >> 2, sub = tid & 3;
    const float* xp = xrow0 + (size_t)row * 128 + sub * 32;
    float4 v[8];
    float s = 0.f, q = 0.f;
    #pragma unroll
    for (int i = 0; i < 8; ++i) {
        v[i] = *(const float4*)(xp + i * 4);
        s += v[i].x + v[i].y + v[i].z + v[i].w;
        q += v[i].x * v[i].x + v[i].y * v[i].y + v[i].z * v[i].z + v[i].w * v[i].w;
    }
    s += __shfl_xor(s, 1); q += __shfl_xor(q, 1);
    s += __shfl_xor(s, 2); q += __shfl_xor(q, 2);
    float mean = s * (1.0f / 128.0f);
    float rs = 1.0f / sqrtf(q * (1.0f / 128.0f) - mean * mean + 1e-5f);
    const float* gp = gl + sub * 32;
    const float* bp = bl + sub * 32;
    #pragma unroll
    for (int i = 0; i < 8; ++i) {
        float4 g4 = *(const float4*)(gp + i * 4);
        float4 b4 = *(const float4*)(bp + i * 4);
        unsigned u0 = cvtpk((v[i].x - mean) * rs * g4.x + b4.x,
                            (v[i].y - mean) * rs * g4.y + b4.y);
        unsigned u1 = cvtpk((v[i].z - mean) * rs * g4.z + b4.z,
                            (v[i].w - mean) * rs * g4.w + b4.w);
        unsigned long long uu = (unsigned long long)u0 | ((unsigned long long)u1 << 32);
        *(unsigned long long*)(&At[row][sub * 32 + i * 4]) = uu;
    }
}

// ---------------- fused LN1 + QKV + RoPE + V-transpose (LDS, 64-row) -------
// 192 blocks x 256 thr: bid<96 Q; [96,144) K; [144,192) V. Each block:
// LN 64 rows -> LDS, then 4 waves x (64r x 32c) covering 64 x 128.
__global__ __launch_bounds__(256) void qkv_lds(const float* __restrict__ xin,
        const short* __restrict__ wbuf, const float* __restrict__ bq,
        const float* __restrict__ bk, const float* __restrict__ bv, int layer,
        const float* __restrict__ gl, const float* __restrict__ bl,
        short* __restrict__ qb, short* __restrict__ kb, short* __restrict__ vt) {
    __shared__ short At[64][136];
    int bid = blockIdx.x;
    int z, by;
    if (bid < 96)       { z = 0; by = bid; }
    else if (bid < 144) { z = 1; by = bid - 96; }
    else                { z = 2; by = bid - 144; }
    const short* Wz = wbuf + (z == 0 ? 0 : z == 1 ? 65536 : 131072) + layer * 16384;
    const float* bz = (z == 0 ? bq : z == 1 ? bk : bv) + layer * 128;
    int r0 = by * 64;
    int gadd = (z > 0) ? (r0 / 1536) * 1536 : 0;   // compact kv row -> global row
    int tid = threadIdx.x;

    ln_to_lds64(At, xin + (size_t)(r0 + gadd) * 128, gl, bl, tid);
    __syncthreads();

    int wv = tid >> 6, l = tid & 63, l31 = l & 31, hi = l >> 5;
    const short* Wb = Wz + (size_t)(wv * 32 + l31) * 128 + hi * 8;
    f32x16 acc[2];
    #pragma unroll
    for (int i = 0; i < 16; ++i) { acc[0][i] = 0.f; acc[1][i] = 0.f; }
    #pragma unroll 8
    for (int k0 = 0; k0 < 128; k0 += 16) {
        bf16x8 a0 = *(const bf16x8*)(&At[l31][k0 + hi * 8]);
        bf16x8 a1 = *(const bf16x8*)(&At[32 + l31][k0 + hi * 8]);
        bf16x8 b  = *(const bf16x8*)(Wb + k0);
        acc[0] = MFMA32(a0, b, acc[0], 0, 0, 0);
        acc[1] = MFMA32(a1, b, acc[1], 0, 0, 0);
    }

    int c = wv * 32 + l31;
    float bb = bz[c];
    int t = (r0 >> 7) % 12;                        // uniform per 64-row block
    if (z < 2) {
        short* dst = z ? kb : qb;
        float sc = z ? 1.0f : 0.25f;               // fold HD^-0.5 into q
        int cc = c & 15, i4 = c & 3;
        float theta = (i4 == 0) ? 1.0f : 1e-4f;
        float ang = (float)t * theta;
        float sn = sinf(ang), cs = cosf(ang);
        #pragma unroll
        for (int mi = 0; mi < 2; ++mi)
        #pragma unroll
        for (int reg = 0; reg < 16; ++reg) {
            float v = acc[mi][reg] + bb;
            float pv = __shfl_xor(v, 4);           // partner column c^4
            float vo = (cc < 4) ? (v * cs + pv * sn)
                     : (cc < 8) ? (v * cs - pv * sn) : v;
            vo *= sc;
            int r = r0 + mi * 32 + CROW(reg);
            dst[(size_t)r * 128 + c] = (short)f2bf(vo);
        }
    } else {
        int d = c & 15, hh = c >> 4, bidx = r0 / 1536;
        #pragma unroll
        for (int mi = 0; mi < 2; ++mi)
        #pragma unroll
        for (int rq = 0; rq < 4; ++rq) {           // regs 4rq..4rq+3 -> kk consecutive
            int rcb = r0 + mi * 32 + 8 * rq + 4 * hi;
            int kk = rcb - bidx * 1536;
            short4v o;
            #pragma unroll
            for (int j = 0; j < 4; ++j) o[j] = (short)f2bf(acc[mi][4 * rq + j] + bb);
            *(short4v*)(vt + ((size_t)(bidx * 8 + hh) * 16 + d) * 1536 + kk) = o;
        }
    }
}

// ---------------- flash attention, split-K partials (unchanged) ------------
__global__ __launch_bounds__(256) void attn_part(const short* __restrict__ qb,
        const short* __restrict__ kb, const short* __restrict__ vt,
        float* __restrict__ part) {
    int bid = blockIdx.x;
    int blk = bid / 3, sp = bid - blk * 3;
    int tq = 11 - (blk >> 5);
    int hb = blk & 31, h = hb >> 2, bs = hb & 3, b = bs >> 1;
    int tid = threadIdx.x;
    int wv = tid >> 6, l = tid & 63, l31 = l & 31, hi = l >> 5;
    int q0 = (bs * 12 + tq) * 128 + wv * 32;
    bf16x8 qf = *(const bf16x8*)(qb + (size_t)(q0 + l31) * 128 + h * 16 + hi * 8);
    const short* kp = kb + (size_t)(b * 1536 + l31) * 128 + h * 16 + hi * 8;
    const short* vp = vt + ((size_t)(b * 8 + h) * 16 + l31) * 1536 + hi * 8;
    bool vload = l31 < 16;
    f32x16 acc, zv;
    #pragma unroll
    for (int i = 0; i < 16; ++i) { acc[i] = 0.f; zv[i] = 0.f; }
    float m = -1e30f, lsum = 0.f;
    int nch = (tq + 1) * 4;
    for (int c = sp; c < nch; c += 3) {
        bf16x8 kf = *(const bf16x8*)(kp + (size_t)c * 32 * 128);
        f32x16 s = MFMA32(kf, qf, zv, 0, 0, 0);    // S^T[key 0..31][q=l31]
        float cm = s[0];
        #pragma unroll
        for (int j = 1; j < 16; ++j) cm = fmaxf(cm, s[j]);
        cm = fmaxf(cm, __shfl_xor(cm, 32));
        float mn = fmaxf(m, cm);
        float corr = __expf(m - mn);
        m = mn;
        float p[16]; float ps = 0.f;
        #pragma unroll
        for (int j = 0; j < 16; ++j) { p[j] = __expf(s[j] - mn); ps += p[j]; }
        ps += __shfl_xor(ps, 32);
        lsum = lsum * corr + ps;
        #pragma unroll
        for (int r = 0; r < 8; ++r) acc[r] *= corr;   // rows>=16 stay 0
        unsigned w0 = cvtpk(p[0],  p[1]),  w1 = cvtpk(p[2],  p[3]);
        unsigned w2 = cvtpk(p[4],  p[5]),  w3 = cvtpk(p[6],  p[7]);
        unsigned w4 = cvtpk(p[8],  p[9]),  w5 = cvtpk(p[10], p[11]);
        unsigned w6 = cvtpk(p[12], p[13]), w7 = cvtpk(p[14], p[15]);
        unsigned t1 = hi ? w0 : w2, t2 = hi ? w1 : w3;
        unsigned t3 = hi ? w4 : w6, t4 = hi ? w5 : w7;
        unsigned x1 = __shfl_xor((int)t1, 32), x2 = __shfl_xor((int)t2, 32);
        unsigned x3 = __shfl_xor((int)t3, 32), x4 = __shfl_xor((int)t4, 32);
        U8 pb1, pb2;
        pb1.u[0] = hi ? x1 : w0;  pb1.u[1] = hi ? x2 : w1;
        pb1.u[2] = hi ? w2 : x1;  pb1.u[3] = hi ? w3 : x2;
        pb2.u[0] = hi ? x3 : w4;  pb2.u[1] = hi ? x4 : w5;
        pb2.u[2] = hi ? w6 : x3;  pb2.u[3] = hi ? w7 : x4;
        bf16x8 vf1, vf2;
        #pragma unroll
        for (int i = 0; i < 8; ++i) { vf1[i] = 0; vf2[i] = 0; }
        if (vload) {
            vf1 = *(const bf16x8*)(vp + c * 32);
            vf2 = *(const bf16x8*)(vp + c * 32 + 16);
        }
        acc = MFMA32(vf1, pb1.v, acc, 0, 0, 0);    // keys c*32+0..15
        acc = MFMA32(vf2, pb2.v, acc, 0, 0, 0);    // keys c*32+16..31
    }
    float* pp = part + ((size_t)bid * 256 + tid) * 10;
    pp[0] = m; pp[1] = lsum;
    #pragma unroll
    for (int j = 0; j < 8; ++j) pp[2 + j] = acc[j];
}

// ---------------- combine 3 partials, normalize, store (unchanged) ---------
__global__ __launch_bounds__(256) void attn_comb(const float* __restrict__ part,
        short* __restrict__ attb) {
    int blk = blockIdx.x;
    int tq = 11 - (blk >> 5);
    int hb = blk & 31, h = hb >> 2, bs = hb & 3;
    int tid = threadIdx.x;
    int wv = tid >> 6, l = tid & 63, l31 = l & 31, hi = l >> 5;
    int q0 = (bs * 12 + tq) * 128 + wv * 32;
    const float* p0 = part + ((size_t)(blk * 3) * 256 + tid) * 10;
    const float* p1 = p0 + 2560;
    const float* p2 = p1 + 2560;
    float m0 = p0[0], m1 = p1[0], m2 = p2[0];
    float mm = fmaxf(fmaxf(m0, m1), m2);
    float e0 = __expf(m0 - mm), e1 = __expf(m1 - mm), e2 = __expf(m2 - mm);
    float lsum = p0[1] * e0 + p1[1] * e1 + p2[1] * e2;
    float linv = 1.0f / lsum;
    short4v o1, o2;
    #pragma unroll
    for (int j = 0; j < 4; ++j)
        o1[j] = (short)f2bf((p0[2 + j] * e0 + p1[2 + j] * e1 + p2[2 + j] * e2) * linv);
    #pragma unroll
    for (int j = 0; j < 4; ++j)
        o2[j] = (short)f2bf((p0[6 + j] * e0 + p1[6 + j] * e1 + p2[6 + j] * e2) * linv);
    size_t base = (size_t)(q0 + l31) * 128 + h * 16;
    *(short4v*)(attb + base + 4 * hi) = o1;        // d = 4hi..4hi+3
    *(short4v*)(attb + base + 8 + 4 * hi) = o2;    // d = 8+4hi..+3
}

// ---------------- GEMM + bias + residual, 64x64 tile, 2 waves --------------
__global__ __launch_bounds__(128) void res_gemm(const short* __restrict__ A,
        const short* __restrict__ W, const float* __restrict__ bias,
        const float* __restrict__ res, float* __restrict__ C, int K) {
    int by = blockIdx.y, bx = blockIdx.x;
    int r0 = by * 64;
    int tid = threadIdx.x, wv = tid >> 6, l = tid & 63, l31 = l & 31, hi = l >> 5;
    int c = bx * 64 + wv * 32 + l31;
    const short* Ab = A + (size_t)(r0 + l31) * K + hi * 8;
    const short* Wb = W + (size_t)c * K + hi * 8;
    f32x16 acc[2];
    #pragma unroll
    for (int i = 0; i < 16; ++i) { acc[0][i] = 0.f; acc[1][i] = 0.f; }
    #pragma unroll 8
    for (int k0 = 0; k0 < K; k0 += 16) {
        bf16x8 a0 = *(const bf16x8*)(Ab + k0);
        bf16x8 a1 = *(const bf16x8*)(Ab + (size_t)32 * K + k0);
        bf16x8 b  = *(const bf16x8*)(Wb + k0);
        acc[0] = MFMA32(a0, b, acc[0], 0, 0, 0);
        acc[1] = MFMA32(a1, b, acc[1], 0, 0, 0);
    }
    float bb = bias[c];
    #pragma unroll
    for (int mi = 0; mi < 2; ++mi)
    #pragma unroll
    for (int reg = 0; reg < 16; ++reg) {
        int r = r0 + mi * 32 + CROW(reg);
        size_t ix = (size_t)r * 128 + c;
        C[ix] = res[ix] + acc[mi][reg] + bb;
    }
}

// ---------------- fused LN2 + FFN1 + GELU (LDS, 64-row) --------------------
// grid (4, 96) x 256 thr; each block 64 rows x 128 cols of the N=512 output.
__global__ __launch_bounds__(256) void ffn1_lds(const float* __restrict__ xin,
        const short* __restrict__ w1l, const float* __restrict__ b1l,
        const float* __restrict__ gl, const float* __restrict__ bl,
        short* __restrict__ H) {
    __shared__ short At[64][136];
    int by = blockIdx.y, bx = blockIdx.x;
    int r0 = by * 64;
    int tid = threadIdx.x;

    ln_to_lds64(At, xin + (size_t)r0 * 128, gl, bl, tid);
    __syncthreads();

    int wv = tid >> 6, l = tid & 63, l31 = l & 31, hi = l >> 5;
    int c = bx * 128 + wv * 32 + l31;
    const short* Wb = w1l + (size_t)c * 128 + hi * 8;
    f32x16 acc[2];
    #pragma unroll
    for (int i = 0; i < 16; ++i) { acc[0][i] = 0.f; acc[1][i] = 0.f; }
    #pragma unroll 8
    for (int k0 = 0; k0 < 128; k0 += 16) {
        bf16x8 a0 = *(const bf16x8*)(&At[l31][k0 + hi * 8]);
        bf16x8 a1 = *(const bf16x8*)(&At[32 + l31][k0 + hi * 8]);
        bf16x8 b  = *(const bf16x8*)(Wb + k0);
        acc[0] = MFMA32(a0, b, acc[0], 0, 0, 0);
        acc[1] = MFMA32(a1, b, acc[1], 0, 0, 0);
    }
    float bb = b1l[c];
    #pragma unroll
    for (int mi = 0; mi < 2; ++mi)
    #pragma unroll
    for (int reg = 0; reg < 16; ++reg) {
        int r = r0 + mi * 32 + CROW(reg);
        float v = acc[mi][reg] + bb;
        v = 0.5f * v * (1.0f + erff(v * 0.70710678118654752f));
        H[(size_t)r * 512 + c] = (short)f2bf(v);
    }
}

// ---------------- Final: out[n] = dot(x[n,:], Wf) + bf ----------------
__global__ __launch_bounds__(256) void final_kernel(const float* __restrict__ x,
        const float* __restrict__ Wf, const float* __restrict__ bf,
        float* __restrict__ out) {
    int wave = threadIdx.x >> 6, lane = threadIdx.x & 63;
    int row = blockIdx.x * 4 + wave;
    float2 xv = *(const float2*)(x + (size_t)row * DIM + lane * 2);
    float2 wv = *(const float2*)(Wf + lane * 2);
    float s = xv.x * wv.x + xv.y * wv.y;
    #pragma unroll
    for (int o = 1; o < 64; o <<= 1) s += __shfl_xor(s, o);
    if (lane == 0) out[row] = s + bf[0];
}

// ---------------- Launch ----------------
extern "C" void kernel_launch(void* const* d_in, const int* in_sizes, int n_in,
                              void* d_out, int out_size, void* d_ws, size_t ws_size,
                              hipStream_t stream) {
    const float* x   = (const float*)d_in[0];
    const float* Wq  = (const float*)d_in[1];
    const float* bq  = (const float*)d_in[2];
    const float* Wk  = (const float*)d_in[3];
    const float* bk  = (const float*)d_in[4];
    const float* Wv  = (const float*)d_in[5];
    const float* bv  = (const float*)d_in[6];
    const float* Wo  = (const float*)d_in[7];
    const float* bo  = (const float*)d_in[8];
    const float* W1  = (const float*)d_in[9];
    const float* b1  = (const float*)d_in[10];
    const float* W2  = (const float*)d_in[11];
    const float* b2  = (const float*)d_in[12];
    const float* g1  = (const float*)d_in[13];
    const float* bn1 = (const float*)d_in[14];
    const float* g2  = (const float*)d_in[15];
    const float* bn2 = (const float*)d_in[16];
    const float* Wf  = (const float*)d_in[17];
    const float* bf  = (const float*)d_in[18];
    float* out = (float*)d_out;

    char* wsb = (char*)d_ws;
    float* xcur  = (float*)(wsb + 0);           // 3 MB fp32
    short* qb    = (short*)(wsb + 4718592);     // 1.5 MB
    short* kb    = (short*)(wsb + 6291456);     // 0.75 MB
    short* vt    = (short*)(wsb + 7077888);     // 0.75 MB  [b][h][d][1536]
    short* attb  = (short*)(wsb + 7864320);     // 1.5 MB
    short* hb    = (short*)(wsb + 9437184);     // 6 MB
    short* wbuf  = (short*)(wsb + 15728640);    // 1.5 MB
    float* partb = (float*)(wsb + 17301504);    // 11.8 MB attn partials

    wconv_kernel<<<768, 256, 0, stream>>>(Wq, Wk, Wv, Wo, W1, W2, wbuf);

    for (int i = 0; i < LAYERS; ++i) {
        const short* wob = wbuf + 196608 + i * 16384;
        const short* w1b = wbuf + 262144 + i * 65536;
        const short* w2b = wbuf + 524288 + i * 65536;
        const float* xin = (i == 0) ? x : xcur;

        qkv_lds<<<192, 256, 0, stream>>>(xin, wbuf, bq, bk, bv, i,
                g1 + i * DIM, bn1 + i * DIM, qb, kb, vt);
        attn_part<<<1152, 256, 0, stream>>>(qb, kb, vt, partb);
        attn_comb<<<384, 256, 0, stream>>>(partb, attb);
        res_gemm<<<dim3(2, 96), 128, 0, stream>>>(attb, wob, bo + i * DIM,
                xin, xcur, 128);
        ffn1_lds<<<dim3(4, 96), 256, 0, stream>>>(xcur, w1b, b1 + i * DFF,
                g2 + i * DIM, bn2 + i * DIM, hb);
        res_gemm<<<dim3(2, 96), 128, 0, stream>>>(hb, w2b, b2 + i * DIM,
                xcur, xcur, 512);
    }
    final_kernel<<<NROWS / 4, 256, 0, stream>>>(xcur, Wf, bf, out);
}